// Round 1
// baseline (428.720 us; speedup 1.0000x reference)
//
#include <hip/hip_runtime.h>
#include <hip/hip_bf16.h>

// Problem constants (from reference)
#define B_    8
#define C_    64
#define P_    64
#define H_    256
#define W_    256
#define BHW_  (B_ * H_ * W_)   // 524288
#define BN_EPS 1e-5f

// Chain tiling: 8 channels per launch, 32x32 interior, halo 8 -> 48x48 load
#define CHUNK 8
#define TS    32
#define RAD   8
#define LS    48           // TS + 2*RAD
#define SW    49           // padded LDS stride

// ---------------------------------------------------------------------------
// Chain kernel: computes ys[c0..c0+7] from src (previous channel image).
// src layout: contiguous (B,H,W) slab (for chunk>0: ys + (c0-1)*BHW).
// For chunk 0, src = x with channel-0 offset handled via src_stride.
// ---------------------------------------------------------------------------
__global__ __launch_bounds__(256) void chain_kernel(
    const float* __restrict__ src,   // base of input image slab
    size_t src_batch_stride,         // C_*H_*W_ for x, H_*W_ for ys slab
    const float* __restrict__ dw,    // dw_w + c0*9
    float* __restrict__ ys,          // ys base (C,B,H,W)
    int c0)
{
    __shared__ float buf0[LS * SW];
    __shared__ float buf1[LS * SW];

    const int tid = threadIdx.x;
    const int b  = blockIdx.z;
    const int ty0 = blockIdx.y * TS;
    const int tx0 = blockIdx.x * TS;

    const float* in = src + (size_t)b * src_batch_stride;

    // Load 48x48 tile (zero outside image)
    for (int t = tid; t < LS * LS; t += 256) {
        int ly = t / LS, lx = t - ly * LS;
        int gy = ty0 - RAD + ly, gx = tx0 - RAD + lx;
        float v = 0.f;
        if (gy >= 0 && gy < H_ && gx >= 0 && gx < W_)
            v = in[gy * W_ + gx];
        buf0[ly * SW + lx] = v;
    }
    __syncthreads();

    float* cur = buf0;
    float* nxt = buf1;

    for (int i = 0; i < CHUNK; ++i) {
        const float w0 = dw[i*9+0], w1 = dw[i*9+1], w2 = dw[i*9+2];
        const float w3 = dw[i*9+3], w4 = dw[i*9+4], w5 = dw[i*9+5];
        const float w6 = dw[i*9+6], w7 = dw[i*9+7], w8 = dw[i*9+8];
        const int lo = 1 + i, hi = 46 - i;   // inclusive valid output region

        for (int t = tid; t < LS * LS; t += 256) {
            int ly = t / LS, lx = t - ly * LS;
            if (ly < lo || ly > hi || lx < lo || lx > hi) continue;
            int gy = ty0 - RAD + ly, gx = tx0 - RAD + lx;
            float v = 0.f;
            if (gy >= 0 && gy < H_ && gx >= 0 && gx < W_) {
                const float* r0 = cur + (ly - 1) * SW + (lx - 1);
                float s = fmaf(r0[0],      w0,
                          fmaf(r0[1],      w1,
                          fmaf(r0[2],      w2,
                          fmaf(r0[SW],     w3,
                          fmaf(r0[SW+1],   w4,
                          fmaf(r0[SW+2],   w5,
                          fmaf(r0[2*SW],   w6,
                          fmaf(r0[2*SW+1], w7,
                               r0[2*SW+2] * w8))))))));
                v = fminf(fmaxf(s, 0.f), 6.f);
            }
            nxt[ly * SW + lx] = v;
            // interior -> global ys
            if (ly >= RAD && ly < RAD + TS && lx >= RAD && lx < RAD + TS) {
                ys[(((size_t)(c0 + i) * B_ + b) * H_ + gy) * W_ + gx] = v;
            }
        }
        __syncthreads();
        float* tmp = cur; cur = nxt; nxt = tmp;
    }
}

// ---------------------------------------------------------------------------
// Fuse kernel: per pixel n, h[p] = sum_c A[p][c]*ys[c][n]  (A = scale*pw_w),
// out[n] = sum_p cw[p] * clip(h[p] + bias[p], 0, 6)
// ---------------------------------------------------------------------------
__global__ __launch_bounds__(256) void fuse_kernel(
    const float* __restrict__ ys,      // (C, BHW)
    const float* __restrict__ pw_w,    // (P, C)
    const float* __restrict__ gamma,
    const float* __restrict__ beta,
    const float* __restrict__ mean,
    const float* __restrict__ var,
    const float* __restrict__ conv_w,  // (1, P)
    float* __restrict__ out)           // (BHW)
{
    __shared__ float As[C_ * P_];    // As[c*64 + p] = pw_w[p][c] * scale[p]
    __shared__ float bias_s[P_];
    __shared__ float cw_s[P_];

    const int tid = threadIdx.x;

    for (int idx = tid; idx < C_ * P_; idx += 256) {
        int p = idx & 63;
        int c = idx >> 6;
        float scale = gamma[p] / sqrtf(var[p] + BN_EPS);
        As[idx] = pw_w[p * C_ + c] * scale;
    }
    if (tid < P_) {
        float scale = gamma[tid] / sqrtf(var[tid] + BN_EPS);
        bias_s[tid] = beta[tid] - mean[tid] * scale;
        cw_s[tid]   = conv_w[tid];
    }
    __syncthreads();

    const size_t n = (size_t)blockIdx.x * 256 + tid;

    float h[P_];
#pragma unroll
    for (int p = 0; p < P_; ++p) h[p] = 0.f;

    const float* yp = ys + n;
#pragma unroll 4
    for (int c = 0; c < C_; ++c) {
        float y = yp[(size_t)c * BHW_];
        const float* arow = &As[c * P_];
#pragma unroll
        for (int p = 0; p < P_; ++p) h[p] = fmaf(arow[p], y, h[p]);
    }

    float acc = 0.f;
#pragma unroll
    for (int p = 0; p < P_; ++p) {
        float v = fminf(fmaxf(h[p] + bias_s[p], 0.f), 6.f);
        acc = fmaf(cw_s[p], v, acc);
    }
    out[n] = acc;
}

// ---------------------------------------------------------------------------
extern "C" void kernel_launch(void* const* d_in, const int* in_sizes, int n_in,
                              void* d_out, int out_size, void* d_ws, size_t ws_size,
                              hipStream_t stream) {
    const float* x      = (const float*)d_in[0];   // (B,C,H,W) — only chan 0 used
    const float* dw_w   = (const float*)d_in[1];   // (C,3,3)
    const float* pw_w   = (const float*)d_in[2];   // (P,C)
    const float* gamma  = (const float*)d_in[3];
    const float* beta   = (const float*)d_in[4];
    const float* mean   = (const float*)d_in[5];
    const float* var    = (const float*)d_in[6];
    const float* conv_w = (const float*)d_in[7];   // (1,P)
    float* out = (float*)d_out;

    float* ys = (float*)d_ws;                      // (C, B, H, W) fp32 = 128 MiB

    dim3 cgrid(W_ / TS, H_ / TS, B_);              // 8,8,8 = 512 blocks

    // chunk 0: seeded by x[:, 0]
    chain_kernel<<<cgrid, 256, 0, stream>>>(
        x, (size_t)C_ * H_ * W_, dw_w, ys, 0);

    // chunks 1..7: seeded by ys[c0-1]
    for (int k = 1; k < C_ / CHUNK; ++k) {
        int c0 = k * CHUNK;
        chain_kernel<<<cgrid, 256, 0, stream>>>(
            ys + (size_t)(c0 - 1) * BHW_, (size_t)H_ * W_,
            dw_w + c0 * 9, ys, c0);
    }

    // fused pointwise + BN + ReLU6 + final 1x1
    fuse_kernel<<<BHW_ / 256, 256, 0, stream>>>(
        ys, pw_w, gamma, beta, mean, var, conv_w, out);
}

// Round 2
// 354.828 us; speedup vs baseline: 1.2082x; 1.2082x over previous
//
#include <hip/hip_runtime.h>
#include <hip/hip_bf16.h>

// Problem constants
#define B_    8
#define C_    64
#define P_    64
#define H_    256
#define W_    256
#define BHW_  (B_ * H_ * W_)   // 524288
#define BN_EPS 1e-5f

// Chain tiling: 8 channels/launch, 32x32 interior, halo 8 -> 48x48 working tile
#define CHUNK 8
#define LS    48
#define SWC   52               // LDS row stride (floats), 16B-aligned rows
#define NT    576              // 48 rows x 12 segs of 4 px = 576 threads
#define BUFSZ ((LS + 2) * SWC + 8)

// ---------------------------------------------------------------------------
// Chain kernel: one float4 row-segment per thread, fixed position across the
// 8 sequential conv steps. Shrinking-validity argument: cell at tile-distance
// d is valid after step i iff d >= i+1; interior (d>=8) valid through step 7.
// Garbage outside the valid region is finite (clamp; fmax kills NaN) and is
// never read by valid cells. Out-of-image cells are forced to 0 every step
// (zero-padding semantics), via a per-thread constant mask.
// ---------------------------------------------------------------------------
__global__ __launch_bounds__(NT) void chain_kernel(
    const float* __restrict__ src,   // previous-channel image slab base
    size_t src_batch_stride,         // C_*H_*W_ for x, H_*W_ for ys slab
    const float* __restrict__ dw,    // dw_w + c0*9
    float* __restrict__ ys,          // ys base (C,B,H,W)
    int c0)
{
    __shared__ float buf0[BUFSZ];
    __shared__ float buf1[BUFSZ];

    const int tid = threadIdx.x;
    const int b   = blockIdx.z;
    const int ty0 = blockIdx.y * 32;
    const int tx0 = blockIdx.x * 32;
    const int row = tid / 12;          // 0..47
    const int seg = tid - row * 12;    // 0..11
    const int lx  = seg * 4;           // 0..44
    const int gy  = ty0 - 8 + row;
    const int gx  = tx0 - 8 + lx;      // multiple of 4 -> whole f4 in/out image
    const bool inImg = (gy >= 0) && (gy < H_) && (gx >= 0) && (gx < W_);
    const float msk = inImg ? 1.0f : 0.0f;

    // initial tile load (zero outside image)
    float4 v = make_float4(0.f, 0.f, 0.f, 0.f);
    if (inImg)
        v = *(const float4*)(src + (size_t)b * src_batch_stride
                             + (size_t)gy * W_ + gx);

    float* cur = buf0;
    float* nxt = buf1;
    const int cell = (row + 1) * SWC + 4 + lx;   // +1 row pad, +4 col pad
    *(float4*)&cur[cell] = v;
    __syncthreads();

    const bool wOK = (row >= 8) && (row < 40) && (seg >= 2) && (seg < 10);
    float* gbase = ys + (size_t)c0 * BHW_ + ((size_t)b * H_ + gy) * W_ + gx;

    const int ro = row * SWC + 4 + lx;           // cell index of (row-1, lx)

    for (int i = 0; i < CHUNK; ++i) {
        const float w0 = dw[i*9+0], w1 = dw[i*9+1], w2 = dw[i*9+2];
        const float w3 = dw[i*9+3], w4 = dw[i*9+4], w5 = dw[i*9+5];
        const float w6 = dw[i*9+6], w7 = dw[i*9+7], w8 = dw[i*9+8];

        // window rows: 6 floats each, lx-1..lx+4, via 4 bank-balanced float2s
        float a[6], e[6], c[6];
        {
            const float* rp = &cur[ro];
            float2 q0 = *(const float2*)(rp - 2);
            float2 q1 = *(const float2*)(rp);
            float2 q2 = *(const float2*)(rp + 2);
            float2 q3 = *(const float2*)(rp + 4);
            a[0]=q0.y; a[1]=q1.x; a[2]=q1.y; a[3]=q2.x; a[4]=q2.y; a[5]=q3.x;
        }
        {
            const float* rp = &cur[ro + SWC];
            float2 q0 = *(const float2*)(rp - 2);
            float2 q1 = *(const float2*)(rp);
            float2 q2 = *(const float2*)(rp + 2);
            float2 q3 = *(const float2*)(rp + 4);
            e[0]=q0.y; e[1]=q1.x; e[2]=q1.y; e[3]=q2.x; e[4]=q2.y; e[5]=q3.x;
        }
        {
            const float* rp = &cur[ro + 2 * SWC];
            float2 q0 = *(const float2*)(rp - 2);
            float2 q1 = *(const float2*)(rp);
            float2 q2 = *(const float2*)(rp + 2);
            float2 q3 = *(const float2*)(rp + 4);
            c[0]=q0.y; c[1]=q1.x; c[2]=q1.y; c[3]=q2.x; c[4]=q2.y; c[5]=q3.x;
        }

        float o[4];
#pragma unroll
        for (int j = 0; j < 4; ++j) {
            float s = fmaf(a[j],   w0,
                      fmaf(a[j+1], w1,
                      fmaf(a[j+2], w2,
                      fmaf(e[j],   w3,
                      fmaf(e[j+1], w4,
                      fmaf(e[j+2], w5,
                      fmaf(c[j],   w6,
                      fmaf(c[j+1], w7,
                           c[j+2] * w8))))))));
            o[j] = fminf(fmaxf(s, 0.f), 6.f) * msk;
        }
        float4 ov = make_float4(o[0], o[1], o[2], o[3]);
        *(float4*)&nxt[cell] = ov;
        if (wOK)
            *(float4*)(gbase + (size_t)i * BHW_) = ov;
        __syncthreads();
        float* t = cur; cur = nxt; nxt = t;
    }
}

// ---------------------------------------------------------------------------
// Fuse kernel, 2 pixels/thread: halves LDS A-read traffic per FMA.
// ---------------------------------------------------------------------------
__global__ __launch_bounds__(256) void fuse_kernel(
    const float* __restrict__ ys,      // (C, BHW)
    const float* __restrict__ pw_w,    // (P, C)
    const float* __restrict__ gamma,
    const float* __restrict__ beta,
    const float* __restrict__ mean,
    const float* __restrict__ var,
    const float* __restrict__ conv_w,  // (1, P)
    float* __restrict__ out)           // (BHW)
{
    __shared__ float As[C_ * P_];      // As[c*64 + p] = pw_w[p][c] * scale[p]
    __shared__ float bias_s[P_];
    __shared__ float cw_s[P_];

    const int tid = threadIdx.x;

    for (int idx = tid; idx < C_ * P_; idx += 256) {
        int p = idx & 63;
        int c = idx >> 6;
        float scale = gamma[p] / sqrtf(var[p] + BN_EPS);
        As[idx] = pw_w[p * C_ + c] * scale;
    }
    if (tid < P_) {
        float scale = gamma[tid] / sqrtf(var[tid] + BN_EPS);
        bias_s[tid] = beta[tid] - mean[tid] * scale;
        cw_s[tid]   = conv_w[tid];
    }
    __syncthreads();

    const size_t n0 = (size_t)blockIdx.x * 512 + tid;
    const size_t n1 = n0 + 256;

    float h0[P_], h1[P_];
#pragma unroll
    for (int p = 0; p < P_; ++p) { h0[p] = 0.f; h1[p] = 0.f; }

    const float* yp = ys;
#pragma unroll 2
    for (int c = 0; c < C_; ++c) {
        float y0 = yp[(size_t)c * BHW_ + n0];
        float y1 = yp[(size_t)c * BHW_ + n1];
        const float* arow = &As[c * P_];
#pragma unroll
        for (int p = 0; p < P_; ++p) {
            float av = arow[p];
            h0[p] = fmaf(av, y0, h0[p]);
            h1[p] = fmaf(av, y1, h1[p]);
        }
    }

    float acc0 = 0.f, acc1 = 0.f;
#pragma unroll
    for (int p = 0; p < P_; ++p) {
        float v0 = fminf(fmaxf(h0[p] + bias_s[p], 0.f), 6.f);
        float v1 = fminf(fmaxf(h1[p] + bias_s[p], 0.f), 6.f);
        acc0 = fmaf(cw_s[p], v0, acc0);
        acc1 = fmaf(cw_s[p], v1, acc1);
    }
    out[n0] = acc0;
    out[n1] = acc1;
}

// ---------------------------------------------------------------------------
extern "C" void kernel_launch(void* const* d_in, const int* in_sizes, int n_in,
                              void* d_out, int out_size, void* d_ws, size_t ws_size,
                              hipStream_t stream) {
    const float* x      = (const float*)d_in[0];   // (B,C,H,W) — only chan 0 used
    const float* dw_w   = (const float*)d_in[1];   // (C,3,3)
    const float* pw_w   = (const float*)d_in[2];   // (P,C)
    const float* gamma  = (const float*)d_in[3];
    const float* beta   = (const float*)d_in[4];
    const float* mean   = (const float*)d_in[5];
    const float* var    = (const float*)d_in[6];
    const float* conv_w = (const float*)d_in[7];   // (1,P)
    float* out = (float*)d_out;

    float* ys = (float*)d_ws;                      // (C, B, H, W) fp32 = 128 MiB

    dim3 cgrid(W_ / 32, H_ / 32, B_);              // 8,8,8 = 512 blocks

    // chunk 0: seeded by x[:, 0]
    chain_kernel<<<cgrid, NT, 0, stream>>>(
        x, (size_t)C_ * H_ * W_, dw_w, ys, 0);

    // chunks 1..7: seeded by ys[c0-1]
    for (int k = 1; k < C_ / CHUNK; ++k) {
        int c0 = k * CHUNK;
        chain_kernel<<<cgrid, NT, 0, stream>>>(
            ys + (size_t)(c0 - 1) * BHW_, (size_t)H_ * W_,
            dw_w + c0 * 9, ys, c0);
    }

    // fused pointwise + BN + ReLU6 + final 1x1  (2 px/thread)
    fuse_kernel<<<BHW_ / 512, 256, 0, stream>>>(
        ys, pw_w, gamma, beta, mean, var, conv_w, out);
}